// Round 3
// baseline (327.289 us; speedup 1.0000x reference)
//
#include <hip/hip_runtime.h>
#include <utility>

// RNN: h_{t+1} = relu(x_t * W_ih^T + b_ih + b_hh + h_t @ W_hh^T), out = h_T @ fc_w^T + fc_b
// B=4096, T=1000, H=20.
//
// Decomposition: 4 lanes per batch element. Lane `sub` (0..3) owns outputs
// j = sub*5 .. sub*5+4 and keeps its 5x20 slice of W_hh in VGPRs (~100 regs).
// The 20 h-values are shared across the quad with DPP quad_perm broadcasts.
//
// R1/R2 lesson: VGPR_Count stayed at 80 and FETCH_SIZE at 8 GB regardless of
// launch bounds -> the compiler SINKS the w[100] loads into the t-loop
// (rematerializes from const __restrict__ W_hh every step) instead of keeping
// them live. Fix: pin each loaded value with an empty asm volatile "+v"
// constraint -- the value becomes an opaque asm output, so it must stay in a
// VGPR and the load cannot be re-sunk.

#define HID 20
#define TT  1000

#define PIN_VGPR(v) asm volatile("" : "+v"(v))

template <int Q>
__device__ __forceinline__ float quad_bcast(float v) {
    // quad_perm ctrl: all four 2-bit selectors = Q -> broadcast lane Q of each quad
    int r = __builtin_amdgcn_update_dpp(0, __float_as_int(v),
                                        (Q * 0x55), 0xF, 0xF, true);
    return __int_as_float(r);
}

template <int K>
__device__ __forceinline__ void fma_k(float (&acc)[5], const float (&w)[100],
                                      const float (&h)[5]) {
    constexpr int q = K / 5;
    constexpr int r = K - q * 5;
    float bk = quad_bcast<q>(h[r]);
#pragma unroll
    for (int j = 0; j < 5; ++j)
        acc[j] = __builtin_fmaf(bk, w[j * HID + K], acc[j]);
}

template <int... Ks>
__device__ __forceinline__ void all_k(float (&acc)[5], const float (&w)[100],
                                      const float (&h)[5],
                                      std::integer_sequence<int, Ks...>) {
    (fma_k<Ks>(acc, w, h), ...);
}

__global__ void __launch_bounds__(64, 1)
rnn_quad_kernel(const float* __restrict__ x,
                const float* __restrict__ W_ih,
                const float* __restrict__ W_hh,
                const float* __restrict__ b_ih,
                const float* __restrict__ b_hh,
                const float* __restrict__ fc_w,
                const float* __restrict__ fc_b,
                float* __restrict__ out) {
    const int tid = blockIdx.x * blockDim.x + threadIdx.x;
    const int b   = tid >> 2;   // batch element, 0..4095
    const int sub = tid & 3;    // lane-in-quad, owns rows sub*5 .. sub*5+4

    // --- per-lane weight slice in registers (amortized over 1000 steps)
    float w[100];
#pragma unroll
    for (int j = 0; j < 5; ++j)
#pragma unroll
        for (int k = 0; k < HID; ++k)
            w[j * HID + k] = W_hh[(sub * 5 + j) * HID + k];

    float wih[5], bias[5];
#pragma unroll
    for (int j = 0; j < 5; ++j) {
        const int row = sub * 5 + j;
        wih[j]  = W_ih[row];
        bias[j] = b_ih[row] + b_hh[row];
    }

    // Pin everything loop-invariant into VGPRs so the compiler cannot sink
    // the loads into the t-loop (R2: that sinking caused 8 GB of HBM refetch).
#pragma unroll
    for (int i = 0; i < 100; ++i) PIN_VGPR(w[i]);
#pragma unroll
    for (int j = 0; j < 5; ++j) { PIN_VGPR(wih[j]); PIN_VGPR(bias[j]); }

    float h[5] = {0.f, 0.f, 0.f, 0.f, 0.f};

    const float* __restrict__ xb = x + (size_t)b * TT;

    for (int t4 = 0; t4 < TT; t4 += 4) {
        const float4 xq = *(const float4*)(xb + t4);  // row stride 4000B, 16B aligned
#pragma unroll
        for (int c = 0; c < 4; ++c) {
            const float xt = (&xq.x)[c];
            float acc[5];
#pragma unroll
            for (int j = 0; j < 5; ++j)
                acc[j] = __builtin_fmaf(xt, wih[j], bias[j]);

            all_k(acc, w, h, std::make_integer_sequence<int, HID>{});

#pragma unroll
            for (int j = 0; j < 5; ++j)
                h[j] = fmaxf(acc[j], 0.f);
        }
    }

    // --- head: out[b] = sum_j h_T[j] * fc_w[j] + fc_b
    float fcw[5];
#pragma unroll
    for (int j = 0; j < 5; ++j)
        fcw[j] = fc_w[sub * 5 + j];

    float dot = 0.f;
#pragma unroll
    for (int j = 0; j < 5; ++j)
        dot = __builtin_fmaf(h[j], fcw[j], dot);

    // quad reduction (xor by 1 and 2 stays inside the quad)
    dot += __shfl_xor(dot, 1, 4);
    dot += __shfl_xor(dot, 2, 4);

    if (sub == 0)
        out[b] = dot + fc_b[0];
}

extern "C" void kernel_launch(void* const* d_in, const int* in_sizes, int n_in,
                              void* d_out, int out_size, void* d_ws, size_t ws_size,
                              hipStream_t stream) {
    const float* x    = (const float*)d_in[0];
    const float* W_ih = (const float*)d_in[1];
    const float* W_hh = (const float*)d_in[2];
    const float* b_ih = (const float*)d_in[3];
    const float* b_hh = (const float*)d_in[4];
    const float* fc_w = (const float*)d_in[5];
    const float* fc_b = (const float*)d_in[6];
    float* out = (float*)d_out;

    // 4096 batches * 4 lanes = 16384 threads; 64-thread blocks -> 256 blocks,
    // one wave per block, spread across all 256 CUs.
    const int block = 64;
    const int grid  = (4096 * 4) / block;  // 256 blocks
    rnn_quad_kernel<<<grid, block, 0, stream>>>(x, W_ih, W_hh, b_ih, b_hh,
                                                fc_w, fc_b, out);
}

// Round 4
// 327.063 us; speedup vs baseline: 1.0007x; 1.0007x over previous
//
#include <hip/hip_runtime.h>
#include <utility>

// RNN: h_{t+1} = relu(x_t * W_ih^T + b_ih + b_hh + h_t @ W_hh^T), out = h_T @ fc_w^T + fc_b
// B=4096, T=1000, H=20.
//
// 4 lanes per batch element; lane `sub` owns rows sub*5..sub*5+4 of W_hh
// (contiguous 100 floats at W_hh + sub*100). h shared across the quad with
// DPP quad_perm broadcasts.
//
// R1-R3 lesson: C arrays (w[100], h[5], acc[5], (&xq.x)[c]) indexed by loop
// variables defeat SROA (it runs BEFORE unrolling) -> alloca survives ->
// every value lives in SCRATCH, re-read each timestep -> 8 GB HBM traffic,
// VGPR_Count stuck at 80. Launch bounds / asm pins can't fix an alloca.
// Fix: recursive-template register struct RA<N> with compile-time-only
// indexing -> constant GEPs -> first SROA pass scalarizes -> guaranteed SSA.

#define HID 20
#define TT  1000

// ---------- guaranteed-register array ----------
template <int N> struct RA { float head; RA<N - 1> tail; };
template <> struct RA<1> { float head; };

template <int I, int N>
__device__ __forceinline__ float& ra(RA<N>& a) {
    if constexpr (I == 0) return a.head;
    else return ra<I - 1>(a.tail);
}
template <int I, int N>
__device__ __forceinline__ const float& ra(const RA<N>& a) {
    if constexpr (I == 0) return a.head;
    else return ra<I - 1>(a.tail);
}

__device__ __forceinline__ void pin1(float& v) { asm volatile("" : "+v"(v)); }

// ---------- DPP quad broadcast ----------
template <int Q>
__device__ __forceinline__ float quad_bcast(float v) {
    // quad_perm ctrl [Q,Q,Q,Q] = Q*0x55 -> broadcast lane Q of each quad
    int r = __builtin_amdgcn_update_dpp(0, __float_as_int(v),
                                        (Q * 0x55), 0xF, 0xF, true);
    return __int_as_float(r);
}

// ---------- compile-time loops ----------
template <int... Is>
__device__ __forceinline__ void load_arr(RA<sizeof...(Is)>& a,
                                         const float* __restrict__ p,
                                         std::integer_sequence<int, Is...>) {
    ((ra<Is>(a) = p[Is]), ...);
}

template <int... Is>
__device__ __forceinline__ void pin_arr(RA<sizeof...(Is)>& a,
                                        std::integer_sequence<int, Is...>) {
    (pin1(ra<Is>(a)), ...);
}

template <int K, int... Js>
__device__ __forceinline__ void fma_k_j(RA<5>& acc, const RA<100>& w, float bk,
                                        std::integer_sequence<int, Js...>) {
    ((ra<Js>(acc) = __builtin_fmaf(bk, ra<Js * HID + K>(w), ra<Js>(acc))), ...);
}

template <int K>
__device__ __forceinline__ void fma_k(RA<5>& acc, const RA<100>& w,
                                      const RA<5>& h) {
    constexpr int q = K / 5;
    constexpr int r = K - q * 5;
    float bk = quad_bcast<q>(ra<r>(h));
    fma_k_j<K>(acc, w, bk, std::make_integer_sequence<int, 5>{});
}

template <int... Ks>
__device__ __forceinline__ void all_k(RA<5>& acc, const RA<100>& w,
                                      const RA<5>& h,
                                      std::integer_sequence<int, Ks...>) {
    (fma_k<Ks>(acc, w, h), ...);
}

template <int... Js>
__device__ __forceinline__ void init_acc(RA<5>& acc, float xt, const RA<5>& wih,
                                         const RA<5>& bias,
                                         std::integer_sequence<int, Js...>) {
    ((ra<Js>(acc) = __builtin_fmaf(xt, ra<Js>(wih), ra<Js>(bias))), ...);
}

template <int... Js>
__device__ __forceinline__ void relu_h(RA<5>& h, const RA<5>& acc,
                                       std::integer_sequence<int, Js...>) {
    ((ra<Js>(h) = fmaxf(ra<Js>(acc), 0.f)), ...);
}

__device__ __forceinline__ void substep(float xt, RA<5>& h, const RA<100>& w,
                                        const RA<5>& wih, const RA<5>& bias) {
    RA<5> acc;
    init_acc(acc, xt, wih, bias, std::make_integer_sequence<int, 5>{});
    all_k(acc, w, h, std::make_integer_sequence<int, HID>{});
    relu_h(h, acc, std::make_integer_sequence<int, 5>{});
}

__global__ void
__attribute__((amdgpu_flat_work_group_size(64, 64), amdgpu_waves_per_eu(1, 1)))
rnn_quad_kernel(const float* __restrict__ x,
                const float* __restrict__ W_ih,
                const float* __restrict__ W_hh,
                const float* __restrict__ b_ih,
                const float* __restrict__ b_hh,
                const float* __restrict__ fc_w,
                const float* __restrict__ fc_b,
                float* __restrict__ out) {
    const int tid = blockIdx.x * blockDim.x + threadIdx.x;
    const int b   = tid >> 2;   // batch element, 0..4095
    const int sub = tid & 3;    // lane-in-quad, owns rows sub*5..sub*5+4

    // lane's 5x20 W_hh slice is contiguous: (sub*5+j)*20+k = sub*100 + (j*20+k)
    RA<100> w;
    load_arr(w, W_hh + sub * 100, std::make_integer_sequence<int, 100>{});

    RA<5> wih, bias;
    {
        const float* __restrict__ pw = W_ih + sub * 5;
        const float* __restrict__ p1 = b_ih + sub * 5;
        const float* __restrict__ p2 = b_hh + sub * 5;
        load_arr(wih, pw, std::make_integer_sequence<int, 5>{});
        RA<5> b1, b2;
        load_arr(b1, p1, std::make_integer_sequence<int, 5>{});
        load_arr(b2, p2, std::make_integer_sequence<int, 5>{});
        ra<0>(bias) = ra<0>(b1) + ra<0>(b2);
        ra<1>(bias) = ra<1>(b1) + ra<1>(b2);
        ra<2>(bias) = ra<2>(b1) + ra<2>(b2);
        ra<3>(bias) = ra<3>(b1) + ra<3>(b2);
        ra<4>(bias) = ra<4>(b1) + ra<4>(b2);
    }

    // keep everything loop-invariant resident in VGPRs
    pin_arr(w, std::make_integer_sequence<int, 100>{});
    pin_arr(wih, std::make_integer_sequence<int, 5>{});
    pin_arr(bias, std::make_integer_sequence<int, 5>{});

    RA<5> h;
    ra<0>(h) = 0.f; ra<1>(h) = 0.f; ra<2>(h) = 0.f; ra<3>(h) = 0.f; ra<4>(h) = 0.f;

    const float* __restrict__ xb = x + (size_t)b * TT;

    for (int t4 = 0; t4 < TT; t4 += 4) {
        const float4 xq = *(const float4*)(xb + t4);  // 16B-aligned (row = 4000B)
        substep(xq.x, h, w, wih, bias);
        substep(xq.y, h, w, wih, bias);
        substep(xq.z, h, w, wih, bias);
        substep(xq.w, h, w, wih, bias);
    }

    // --- head: out[b] = sum_j h_T[j] * fc_w[j] + fc_b
    RA<5> fcw;
    load_arr(fcw, fc_w + sub * 5, std::make_integer_sequence<int, 5>{});

    float dot = 0.f;
    dot = __builtin_fmaf(ra<0>(h), ra<0>(fcw), dot);
    dot = __builtin_fmaf(ra<1>(h), ra<1>(fcw), dot);
    dot = __builtin_fmaf(ra<2>(h), ra<2>(fcw), dot);
    dot = __builtin_fmaf(ra<3>(h), ra<3>(fcw), dot);
    dot = __builtin_fmaf(ra<4>(h), ra<4>(fcw), dot);

    // quad reduction (xor 1, xor 2 stay inside the quad)
    dot += __shfl_xor(dot, 1, 4);
    dot += __shfl_xor(dot, 2, 4);

    if (sub == 0)
        out[b] = dot + fc_b[0];
}

extern "C" void kernel_launch(void* const* d_in, const int* in_sizes, int n_in,
                              void* d_out, int out_size, void* d_ws, size_t ws_size,
                              hipStream_t stream) {
    const float* x    = (const float*)d_in[0];
    const float* W_ih = (const float*)d_in[1];
    const float* W_hh = (const float*)d_in[2];
    const float* b_ih = (const float*)d_in[3];
    const float* b_hh = (const float*)d_in[4];
    const float* fc_w = (const float*)d_in[5];
    const float* fc_b = (const float*)d_in[6];
    float* out = (float*)d_out;

    // 4096 batches * 4 lanes = 16384 threads; 64-thread blocks -> 256 blocks
    // spread over all 256 CUs (1 wave per CU).
    const int block = 64;
    const int grid  = (4096 * 4) / block;  // 256 blocks
    rnn_quad_kernel<<<grid, block, 0, stream>>>(x, W_ih, W_hh, b_ih, b_hh,
                                                fc_w, fc_b, out);
}

// Round 5
// 244.040 us; speedup vs baseline: 1.3411x; 1.3402x over previous
//
#include <hip/hip_runtime.h>

// RNN: h_{t+1} = relu(x_t*W_ih^T + b_ih + b_hh + W_hh·h_t), out = fc(h_T).
// B=4096, T=1000, H=20.
//
// R4 lesson: FETCH_SIZE is KB -> only 8 MB of HBM traffic; kernel was always
// issue/latency-bound with 1 wave per CU (256 waves on 1024 SIMDs, VALUBusy
// 19% = one SIMD ~76% busy). Fix: 16 lanes per batch -> 1024 waves fill ALL
// 1024 SIMDs, and per-wave work drops to 25 FMAs/step.
//
// Lane (jg,kg), jg=rows jg*5..jg*5+4, kg=k-slice kg*5..kg*5+4:
//   acc_j = [kg==0]*(x*wih_j + bias_j) + sum_i h[kg*5+i]*W[row_j][kg*5+i]
//   quad butterfly (DPP quad_perm xor1,xor2) -> full pre-activation in all
//   4 lanes of quad jg; relu -> h_own = h[jg-slice].
//   Redistribute: DPP row_ror:4/8/12 bring other quads' slices; 3 cndmask
//   selects pick the slice == kg. Rotation direction SELF-CALIBRATED at init
//   (rotate jg itself, compare) so the ror convention cannot break us.
// All cross-lane traffic is full-rate VALU DPP -- no LDS pipe in the loop.

#define TT 1000

struct F5 { float v0, v1, v2, v3, v4; };

template <int CTRL>
__device__ __forceinline__ float dpp_f(float v) {
    return __int_as_float(__builtin_amdgcn_update_dpp(
        0, __float_as_int(v), CTRL, 0xF, 0xF, true));
}
template <int CTRL>
__device__ __forceinline__ int dpp_i(int v) {
    return __builtin_amdgcn_update_dpp(0, v, CTRL, 0xF, 0xF, true);
}

#define QP_XOR1 0xB1   // quad_perm [1,0,3,2]
#define QP_XOR2 0x4E   // quad_perm [2,3,0,1]
#define ROR4  0x124    // row_ror:4
#define ROR8  0x128    // row_ror:8
#define ROR12 0x12C    // row_ror:12

__device__ __forceinline__ float sel4(float own, float r1, float r2, float r3,
                                      bool mo, bool m1, bool m2) {
    return mo ? own : (m1 ? r1 : (m2 ? r2 : r3));
}

#define ROWFMA(a, w)                         \
    a = __builtin_fmaf(hn.v0, (w).v0, a);    \
    a = __builtin_fmaf(hn.v1, (w).v1, a);    \
    a = __builtin_fmaf(hn.v2, (w).v2, a);    \
    a = __builtin_fmaf(hn.v3, (w).v3, a);    \
    a = __builtin_fmaf(hn.v4, (w).v4, a);

__device__ __forceinline__ void step(float xt, F5& hn, F5& hown,
                                     const F5& w0, const F5& w1, const F5& w2,
                                     const F5& w3, const F5& w4,
                                     const F5& wih, const F5& bias,
                                     bool mo, bool m1, bool m2) {
    float a0 = __builtin_fmaf(xt, wih.v0, bias.v0);
    float a1 = __builtin_fmaf(xt, wih.v1, bias.v1);
    float a2 = __builtin_fmaf(xt, wih.v2, bias.v2);
    float a3 = __builtin_fmaf(xt, wih.v3, bias.v3);
    float a4 = __builtin_fmaf(xt, wih.v4, bias.v4);

    ROWFMA(a0, w0) ROWFMA(a1, w1) ROWFMA(a2, w2) ROWFMA(a3, w3) ROWFMA(a4, w4)

    // quad all-reduce over kg (butterfly)
    a0 += dpp_f<QP_XOR1>(a0); a1 += dpp_f<QP_XOR1>(a1); a2 += dpp_f<QP_XOR1>(a2);
    a3 += dpp_f<QP_XOR1>(a3); a4 += dpp_f<QP_XOR1>(a4);
    a0 += dpp_f<QP_XOR2>(a0); a1 += dpp_f<QP_XOR2>(a1); a2 += dpp_f<QP_XOR2>(a2);
    a3 += dpp_f<QP_XOR2>(a3); a4 += dpp_f<QP_XOR2>(a4);

    hown.v0 = fmaxf(a0, 0.f); hown.v1 = fmaxf(a1, 0.f); hown.v2 = fmaxf(a2, 0.f);
    hown.v3 = fmaxf(a3, 0.f); hown.v4 = fmaxf(a4, 0.f);

    // rotate other quads' slices in, select the one matching kg
    {
        float r1 = dpp_f<ROR4>(hown.v0), r2 = dpp_f<ROR8>(hown.v0), r3 = dpp_f<ROR12>(hown.v0);
        hn.v0 = sel4(hown.v0, r1, r2, r3, mo, m1, m2);
    }
    {
        float r1 = dpp_f<ROR4>(hown.v1), r2 = dpp_f<ROR8>(hown.v1), r3 = dpp_f<ROR12>(hown.v1);
        hn.v1 = sel4(hown.v1, r1, r2, r3, mo, m1, m2);
    }
    {
        float r1 = dpp_f<ROR4>(hown.v2), r2 = dpp_f<ROR8>(hown.v2), r3 = dpp_f<ROR12>(hown.v2);
        hn.v2 = sel4(hown.v2, r1, r2, r3, mo, m1, m2);
    }
    {
        float r1 = dpp_f<ROR4>(hown.v3), r2 = dpp_f<ROR8>(hown.v3), r3 = dpp_f<ROR12>(hown.v3);
        hn.v3 = sel4(hown.v3, r1, r2, r3, mo, m1, m2);
    }
    {
        float r1 = dpp_f<ROR4>(hown.v4), r2 = dpp_f<ROR8>(hown.v4), r3 = dpp_f<ROR12>(hown.v4);
        hn.v4 = sel4(hown.v4, r1, r2, r3, mo, m1, m2);
    }
}

__global__ void __launch_bounds__(256)
rnn16_kernel(const float* __restrict__ x,
             const float* __restrict__ W_ih,
             const float* __restrict__ W_hh,
             const float* __restrict__ b_ih,
             const float* __restrict__ b_hh,
             const float* __restrict__ fc_w,
             const float* __restrict__ fc_b,
             float* __restrict__ out) {
    const int tid = blockIdx.x * 256 + threadIdx.x;
    const int b   = tid >> 4;       // batch element, 0..4095
    const int gl  = tid & 15;       // lane within 16-lane group (DPP row-aligned)
    const int jg  = gl >> 2;        // output row group (5 rows)
    const int kg  = gl & 3;         // k-slice group (5 k's)

    // 5x5 weight tile: rows jg*5+j, cols kg*5+i
    F5 w0, w1, w2, w3, w4;
#define LOADW(wj, j) { const float* p = W_hh + (jg * 5 + (j)) * 20 + kg * 5; \
    (wj).v0 = p[0]; (wj).v1 = p[1]; (wj).v2 = p[2]; (wj).v3 = p[3]; (wj).v4 = p[4]; }
    LOADW(w0, 0) LOADW(w1, 1) LOADW(w2, 2) LOADW(w3, 3) LOADW(w4, 4)
#undef LOADW

    // input-projection weights + bias, contributed by kg==0 lanes only
    const bool k0 = (kg == 0);
    F5 wih, bias;
    {
        const float* pw = W_ih + jg * 5;
        const float* p1 = b_ih + jg * 5;
        const float* p2 = b_hh + jg * 5;
        wih.v0  = k0 ? pw[0] : 0.f;  bias.v0 = k0 ? (p1[0] + p2[0]) : 0.f;
        wih.v1  = k0 ? pw[1] : 0.f;  bias.v1 = k0 ? (p1[1] + p2[1]) : 0.f;
        wih.v2  = k0 ? pw[2] : 0.f;  bias.v2 = k0 ? (p1[2] + p2[2]) : 0.f;
        wih.v3  = k0 ? pw[3] : 0.f;  bias.v3 = k0 ? (p1[3] + p2[3]) : 0.f;
        wih.v4  = k0 ? pw[4] : 0.f;  bias.v4 = k0 ? (p1[4] + p2[4]) : 0.f;
    }

    // self-calibrate rotation direction: rotate jg itself, see whose slice lands here
    const int s1 = dpp_i<ROR4>(jg);
    const int s2 = dpp_i<ROR8>(jg);
    const bool mo = (kg == jg);
    const bool m1 = (kg == s1);
    const bool m2 = (kg == s2);

    F5 hn   = {0.f, 0.f, 0.f, 0.f, 0.f};   // h[kg-slice], input to this step
    F5 hown = {0.f, 0.f, 0.f, 0.f, 0.f};   // h[jg-slice], output of this step

    const float* __restrict__ xb = x + (size_t)b * TT;

    // depth-2 software pipeline on the x stream (load ~8 steps ahead)
    float4 cur = *(const float4*)(xb);
    float4 nxt = *(const float4*)(xb + 4);
    for (int t4 = 0; t4 < TT; t4 += 4) {
        int tpre = t4 + 8;
        if (tpre > TT - 4) tpre = TT - 4;
        const float4 nn = *(const float4*)(xb + tpre);

        step(cur.x, hn, hown, w0, w1, w2, w3, w4, wih, bias, mo, m1, m2);
        step(cur.y, hn, hown, w0, w1, w2, w3, w4, wih, bias, mo, m1, m2);
        step(cur.z, hn, hown, w0, w1, w2, w3, w4, wih, bias, mo, m1, m2);
        step(cur.w, hn, hown, w0, w1, w2, w3, w4, wih, bias, mo, m1, m2);

        cur = nxt;
        nxt = nn;
    }

    // head: out[b] = sum_r h_T[r]*fc_w[r] + fc_b.
    // hown = h[jg-slice], replicated across the quad -> mask fcw to kg==0 lanes.
    F5 fcw;
    {
        const float* pf = fc_w + jg * 5;
        fcw.v0 = k0 ? pf[0] : 0.f; fcw.v1 = k0 ? pf[1] : 0.f;
        fcw.v2 = k0 ? pf[2] : 0.f; fcw.v3 = k0 ? pf[3] : 0.f;
        fcw.v4 = k0 ? pf[4] : 0.f;
    }
    float dot = hown.v0 * fcw.v0;
    dot = __builtin_fmaf(hown.v1, fcw.v1, dot);
    dot = __builtin_fmaf(hown.v2, fcw.v2, dot);
    dot = __builtin_fmaf(hown.v3, fcw.v3, dot);
    dot = __builtin_fmaf(hown.v4, fcw.v4, dot);

    // reduce across the 16-lane group (one-time cost; shfl is fine here)
    dot += __shfl_xor(dot, 1, 16);
    dot += __shfl_xor(dot, 2, 16);
    dot += __shfl_xor(dot, 4, 16);
    dot += __shfl_xor(dot, 8, 16);

    if (gl == 0)
        out[b] = dot + fc_b[0];
}

extern "C" void kernel_launch(void* const* d_in, const int* in_sizes, int n_in,
                              void* d_out, int out_size, void* d_ws, size_t ws_size,
                              hipStream_t stream) {
    const float* x    = (const float*)d_in[0];
    const float* W_ih = (const float*)d_in[1];
    const float* W_hh = (const float*)d_in[2];
    const float* b_ih = (const float*)d_in[3];
    const float* b_hh = (const float*)d_in[4];
    const float* fc_w = (const float*)d_in[5];
    const float* fc_b = (const float*)d_in[6];
    float* out = (float*)d_out;

    // 4096 batches * 16 lanes = 65536 threads = 1024 waves -> every SIMD busy.
    const int block = 256;
    const int grid  = (4096 * 16) / block;  // 256 blocks, 4 waves each
    rnn16_kernel<<<grid, block, 0, stream>>>(x, W_ih, W_hh, b_ih, b_hh,
                                             fc_w, fc_b, out);
}

// Round 6
// 194.730 us; speedup vs baseline: 1.6807x; 1.2532x over previous
//
#include <hip/hip_runtime.h>

// RNN: h_{t+1} = relu(x_t*W_ih^T + b_ih + b_hh + W_hh·h_t), out = fc(h_T).
// B=4096, T=1000, H=20.  16 lanes per batch -> 1024 waves = 1 per SIMD.
//
// R5 lessons: (1) VGPR_Count=36 -> compiler sank the 25 weight loads into the
// t-loop (L1/L2 reloads every step, invisible in FETCH_SIZE). Must PIN loaded
// values (R4's trick). (2) 30 of 85 step insts were redistribution
// (row_ror + cndmask selects).
//
// This version: ALTERNATING-ROLE scheme kills redistribution entirely.
// Lane (a,b) of the 16-lane group (a=gl>>2 quad, b=gl&3 pos-in-quad):
//   EVEN step: rows a-group, k-slice b, tile We=W[5a:5a+5, 5b:5b+5].
//     Reduce over b = intra-quad butterfly (quad_perm xor1/xor2).
//     Result h[a-slice] replicated in quad a == k-slice a for the ODD step.
//   ODD step: rows b-group, k-slice a, tile Wo=W[5b:5b+5, 5a:5a+5].
//     Reduce over a = cross-quad rotation allreduce (row_ror:4, row_ror:8;
//     v+ror4+ror8+ror12 in two folds, rotation-direction agnostic).
//     Result h[b-slice] == k-slice b for the next EVEN step.
// Input projection added by exactly one lane per reduction set (b==0 on even
// steps, a==0 on odd steps) via pre-masked wih/bias registers.
// Per step: 5 init-fma + 25 fma + 10 dpp + 10 add(folded) + 5 max = 55 VALU.

#define TT 1000

struct F5 { float v0, v1, v2, v3, v4; };

#define PIN(v) asm volatile("" : "+v"(v))
__device__ __forceinline__ void pin5(F5& f) {
    PIN(f.v0); PIN(f.v1); PIN(f.v2); PIN(f.v3); PIN(f.v4);
}

template <int CTRL>
__device__ __forceinline__ float dpp_f(float v) {
    return __int_as_float(__builtin_amdgcn_update_dpp(
        0, __float_as_int(v), CTRL, 0xF, 0xF, true));
}

#define QP_XOR1 0xB1   // quad_perm [1,0,3,2]
#define QP_XOR2 0x4E   // quad_perm [2,3,0,1]
#define ROR4   0x124   // row_ror:4  (16-lane row)
#define ROR8   0x128   // row_ror:8

#define ROWFMA(a, w)                         \
    a = __builtin_fmaf(h.v0, (w).v0, a);     \
    a = __builtin_fmaf(h.v1, (w).v1, a);     \
    a = __builtin_fmaf(h.v2, (w).v2, a);     \
    a = __builtin_fmaf(h.v3, (w).v3, a);     \
    a = __builtin_fmaf(h.v4, (w).v4, a);

// One timestep. C1/C2 select the reduction pattern:
//   even: quad_perm xor1 / xor2 (sum over b within quad)
//   odd : row_ror:4 / row_ror:8 (sum over a across quads)
template <int C1, int C2>
__device__ __forceinline__ void step(float xt, F5& h,
                                     const F5& w0, const F5& w1, const F5& w2,
                                     const F5& w3, const F5& w4,
                                     const F5& wih, const F5& bias) {
    float a0 = __builtin_fmaf(xt, wih.v0, bias.v0);
    float a1 = __builtin_fmaf(xt, wih.v1, bias.v1);
    float a2 = __builtin_fmaf(xt, wih.v2, bias.v2);
    float a3 = __builtin_fmaf(xt, wih.v3, bias.v3);
    float a4 = __builtin_fmaf(xt, wih.v4, bias.v4);

    ROWFMA(a0, w0) ROWFMA(a1, w1) ROWFMA(a2, w2) ROWFMA(a3, w3) ROWFMA(a4, w4)

    a0 += dpp_f<C1>(a0); a1 += dpp_f<C1>(a1); a2 += dpp_f<C1>(a2);
    a3 += dpp_f<C1>(a3); a4 += dpp_f<C1>(a4);
    a0 += dpp_f<C2>(a0); a1 += dpp_f<C2>(a1); a2 += dpp_f<C2>(a2);
    a3 += dpp_f<C2>(a3); a4 += dpp_f<C2>(a4);

    h.v0 = fmaxf(a0, 0.f); h.v1 = fmaxf(a1, 0.f); h.v2 = fmaxf(a2, 0.f);
    h.v3 = fmaxf(a3, 0.f); h.v4 = fmaxf(a4, 0.f);
}

__global__ void __launch_bounds__(256, 1)
rnn_alt_kernel(const float* __restrict__ x,
               const float* __restrict__ W_ih,
               const float* __restrict__ W_hh,
               const float* __restrict__ b_ih,
               const float* __restrict__ b_hh,
               const float* __restrict__ fc_w,
               const float* __restrict__ fc_b,
               float* __restrict__ out) {
    const int tid = blockIdx.x * 256 + threadIdx.x;
    const int b   = tid >> 4;     // batch element
    const int gl  = tid & 15;     // lane in 16-lane group (DPP-row aligned)
    const int a   = gl >> 2;      // quad index
    const int bq  = gl & 3;       // position in quad

    // --- weight tiles (pinned into VGPRs; R5: unpinned -> per-step reloads)
    F5 we0, we1, we2, we3, we4;   // EVEN: rows a-group, cols bq-group
    F5 wo0, wo1, wo2, wo3, wo4;   // ODD:  rows bq-group, cols a-group
#define LOADW(wj, r, c) { const float* p = W_hh + (r) * 20 + (c);            \
    (wj).v0 = p[0]; (wj).v1 = p[1]; (wj).v2 = p[2]; (wj).v3 = p[3]; (wj).v4 = p[4]; }
    LOADW(we0, a * 5 + 0, bq * 5) LOADW(we1, a * 5 + 1, bq * 5)
    LOADW(we2, a * 5 + 2, bq * 5) LOADW(we3, a * 5 + 3, bq * 5)
    LOADW(we4, a * 5 + 4, bq * 5)
    LOADW(wo0, bq * 5 + 0, a * 5) LOADW(wo1, bq * 5 + 1, a * 5)
    LOADW(wo2, bq * 5 + 2, a * 5) LOADW(wo3, bq * 5 + 3, a * 5)
    LOADW(wo4, bq * 5 + 4, a * 5)
#undef LOADW

    // --- input-projection weights+bias, pre-masked to the contributing lane
    const bool eact = (bq == 0);  // even steps: reduction over b -> b==0 adds
    const bool oact = (a == 0);   // odd steps:  reduction over a -> a==0 adds
    F5 wie, bie, wio, bio;
    {
        const float* pw = W_ih + a * 5;
        const float* p1 = b_ih + a * 5;
        const float* p2 = b_hh + a * 5;
        wie.v0 = eact ? pw[0] : 0.f;  bie.v0 = eact ? (p1[0] + p2[0]) : 0.f;
        wie.v1 = eact ? pw[1] : 0.f;  bie.v1 = eact ? (p1[1] + p2[1]) : 0.f;
        wie.v2 = eact ? pw[2] : 0.f;  bie.v2 = eact ? (p1[2] + p2[2]) : 0.f;
        wie.v3 = eact ? pw[3] : 0.f;  bie.v3 = eact ? (p1[3] + p2[3]) : 0.f;
        wie.v4 = eact ? pw[4] : 0.f;  bie.v4 = eact ? (p1[4] + p2[4]) : 0.f;
    }
    {
        const float* pw = W_ih + bq * 5;
        const float* p1 = b_ih + bq * 5;
        const float* p2 = b_hh + bq * 5;
        wio.v0 = oact ? pw[0] : 0.f;  bio.v0 = oact ? (p1[0] + p2[0]) : 0.f;
        wio.v1 = oact ? pw[1] : 0.f;  bio.v1 = oact ? (p1[1] + p2[1]) : 0.f;
        wio.v2 = oact ? pw[2] : 0.f;  bio.v2 = oact ? (p1[2] + p2[2]) : 0.f;
        wio.v3 = oact ? pw[3] : 0.f;  bio.v3 = oact ? (p1[3] + p2[3]) : 0.f;
        wio.v4 = oact ? pw[4] : 0.f;  bio.v4 = oact ? (p1[4] + p2[4]) : 0.f;
    }

    // pin everything loop-invariant so loads cannot be sunk into the t-loop
    pin5(we0); pin5(we1); pin5(we2); pin5(we3); pin5(we4);
    pin5(wo0); pin5(wo1); pin5(wo2); pin5(wo3); pin5(wo4);
    pin5(wie); pin5(bie); pin5(wio); pin5(bio);

    F5 h = {0.f, 0.f, 0.f, 0.f, 0.f};

    const float* __restrict__ xb = x + (size_t)b * TT;

    // depth-2 pipeline on the x stream
    float4 cur = *(const float4*)(xb);
    float4 nxt = *(const float4*)(xb + 4);
    for (int t4 = 0; t4 < TT; t4 += 4) {
        int tpre = t4 + 8;
        if (tpre > TT - 4) tpre = TT - 4;
        const float4 nn = *(const float4*)(xb + tpre);

        step<QP_XOR1, QP_XOR2>(cur.x, h, we0, we1, we2, we3, we4, wie, bie);
        step<ROR4,    ROR8   >(cur.y, h, wo0, wo1, wo2, wo3, wo4, wio, bio);
        step<QP_XOR1, QP_XOR2>(cur.z, h, we0, we1, we2, we3, we4, wie, bie);
        step<ROR4,    ROR8   >(cur.w, h, wo0, wo1, wo2, wo3, wo4, wio, bio);

        cur = nxt;
        nxt = nn;
    }

    // After the final (odd) step, lane (a,bq) holds h[bq-slice], replicated
    // over a. Mask the fc weights to a==0 lanes, dot, reduce over the group.
    float dot;
    {
        const float* pf = fc_w + bq * 5;
        float f0 = oact ? pf[0] : 0.f, f1 = oact ? pf[1] : 0.f;
        float f2 = oact ? pf[2] : 0.f, f3 = oact ? pf[3] : 0.f;
        float f4 = oact ? pf[4] : 0.f;
        dot = h.v0 * f0;
        dot = __builtin_fmaf(h.v1, f1, dot);
        dot = __builtin_fmaf(h.v2, f2, dot);
        dot = __builtin_fmaf(h.v3, f3, dot);
        dot = __builtin_fmaf(h.v4, f4, dot);
    }
    dot += __shfl_xor(dot, 1, 16);
    dot += __shfl_xor(dot, 2, 16);
    dot += __shfl_xor(dot, 4, 16);
    dot += __shfl_xor(dot, 8, 16);

    if (gl == 0)
        out[b] = dot + fc_b[0];
}

extern "C" void kernel_launch(void* const* d_in, const int* in_sizes, int n_in,
                              void* d_out, int out_size, void* d_ws, size_t ws_size,
                              hipStream_t stream) {
    const float* x    = (const float*)d_in[0];
    const float* W_ih = (const float*)d_in[1];
    const float* W_hh = (const float*)d_in[2];
    const float* b_ih = (const float*)d_in[3];
    const float* b_hh = (const float*)d_in[4];
    const float* fc_w = (const float*)d_in[5];
    const float* fc_b = (const float*)d_in[6];
    float* out = (float*)d_out;

    // 4096 batches * 16 lanes = 65536 threads = 1024 waves -> every SIMD busy.
    const int block = 256;
    const int grid  = (4096 * 16) / block;  // 256 blocks, 4 waves each
    rnn_alt_kernel<<<grid, block, 0, stream>>>(x, W_ih, W_hh, b_ih, b_hh,
                                               fc_w, fc_b, out);
}

// Round 7
// 192.820 us; speedup vs baseline: 1.6974x; 1.0099x over previous
//
#include <hip/hip_runtime.h>

// RNN: h_{t+1} = relu(x_t*W_ih^T + b_ih + b_hh + W_hh·h_t), out = fc(h_T).
// B=4096, T=1000, H=20.  16 lanes per batch, 1024 waves = 1 per SIMD.
//
// Alternating-role scheme (R6): lane (a,bq) of each 16-lane group:
//   EVEN step: rows a-group x k-slice bq; reduce over bq = quad_perm butterfly.
//     Output h[a-slice] replicated in quad a == k-slice a for the odd step.
//   ODD step: rows bq-group x k-slice a (transposed tile); reduce over a =
//     cross-quad rotation allreduce (row_ror:4 + row_ror:8 folds).
//     Output h[bq-slice] == k-slice bq for the next even step.
// Zero redistribution instructions; 55 VALU/step.
//
// R6 lesson: __launch_bounds__(256,1) did NOT lift the VGPR budget —
// VGPR_Count=56 = weights(50)+h(5)+1, the masked wih/bias F5s were reloaded
// every step (~32 extra insts + vmcnt stalls = 336 cyc/step vs 110 ideal).
// R4 proved amdgpu_flat_work_group_size + amdgpu_waves_per_eu(1,1) gives real
// residency (VGPR 132). Use that combo + post-loop keep-alives.

#define TT 1000

struct F5 { float v0, v1, v2, v3, v4; };

#define PIN(v) asm volatile("" : "+v"(v))
__device__ __forceinline__ void pin5(F5& f) {
    PIN(f.v0); PIN(f.v1); PIN(f.v2); PIN(f.v3); PIN(f.v4);
}
// post-loop consume: forces the live range across the whole loop
__device__ __forceinline__ void keep5(const F5& f) {
    asm volatile("" :: "v"(f.v0), "v"(f.v1), "v"(f.v2), "v"(f.v3), "v"(f.v4));
}

template <int CTRL>
__device__ __forceinline__ float dpp_f(float v) {
    return __int_as_float(__builtin_amdgcn_update_dpp(
        0, __float_as_int(v), CTRL, 0xF, 0xF, true));
}

#define QP_XOR1 0xB1   // quad_perm [1,0,3,2]
#define QP_XOR2 0x4E   // quad_perm [2,3,0,1]
#define ROR4   0x124   // row_ror:4  (within 16-lane row)
#define ROR8   0x128   // row_ror:8

#define ROWFMA(a, w)                         \
    a = __builtin_fmaf(h.v0, (w).v0, a);     \
    a = __builtin_fmaf(h.v1, (w).v1, a);     \
    a = __builtin_fmaf(h.v2, (w).v2, a);     \
    a = __builtin_fmaf(h.v3, (w).v3, a);     \
    a = __builtin_fmaf(h.v4, (w).v4, a);

template <int C1, int C2>
__device__ __forceinline__ void step(float xt, F5& h,
                                     const F5& w0, const F5& w1, const F5& w2,
                                     const F5& w3, const F5& w4,
                                     const F5& wih, const F5& bias) {
    float a0 = __builtin_fmaf(xt, wih.v0, bias.v0);
    float a1 = __builtin_fmaf(xt, wih.v1, bias.v1);
    float a2 = __builtin_fmaf(xt, wih.v2, bias.v2);
    float a3 = __builtin_fmaf(xt, wih.v3, bias.v3);
    float a4 = __builtin_fmaf(xt, wih.v4, bias.v4);

    ROWFMA(a0, w0) ROWFMA(a1, w1) ROWFMA(a2, w2) ROWFMA(a3, w3) ROWFMA(a4, w4)

    a0 += dpp_f<C1>(a0); a1 += dpp_f<C1>(a1); a2 += dpp_f<C1>(a2);
    a3 += dpp_f<C1>(a3); a4 += dpp_f<C1>(a4);
    a0 += dpp_f<C2>(a0); a1 += dpp_f<C2>(a1); a2 += dpp_f<C2>(a2);
    a3 += dpp_f<C2>(a3); a4 += dpp_f<C2>(a4);

    h.v0 = fmaxf(a0, 0.f); h.v1 = fmaxf(a1, 0.f); h.v2 = fmaxf(a2, 0.f);
    h.v3 = fmaxf(a3, 0.f); h.v4 = fmaxf(a4, 0.f);
}

__global__ void
__attribute__((amdgpu_flat_work_group_size(64, 64), amdgpu_waves_per_eu(1, 1)))
rnn_alt2_kernel(const float* __restrict__ x,
                const float* __restrict__ W_ih,
                const float* __restrict__ W_hh,
                const float* __restrict__ b_ih,
                const float* __restrict__ b_hh,
                const float* __restrict__ fc_w,
                const float* __restrict__ fc_b,
                float* __restrict__ out) {
    const int tid = blockIdx.x * 64 + threadIdx.x;
    const int b   = tid >> 4;     // batch element
    const int gl  = tid & 15;     // lane in 16-lane group (DPP-row aligned)
    const int a   = gl >> 2;      // quad index
    const int bq  = gl & 3;       // position in quad

    // --- weight tiles
    F5 we0, we1, we2, we3, we4;   // EVEN: rows a-group, cols bq-group
    F5 wo0, wo1, wo2, wo3, wo4;   // ODD:  rows bq-group, cols a-group
#define LOADW(wj, r, c) { const float* p = W_hh + (r) * 20 + (c);            \
    (wj).v0 = p[0]; (wj).v1 = p[1]; (wj).v2 = p[2]; (wj).v3 = p[3]; (wj).v4 = p[4]; }
    LOADW(we0, a * 5 + 0, bq * 5) LOADW(we1, a * 5 + 1, bq * 5)
    LOADW(we2, a * 5 + 2, bq * 5) LOADW(we3, a * 5 + 3, bq * 5)
    LOADW(we4, a * 5 + 4, bq * 5)
    LOADW(wo0, bq * 5 + 0, a * 5) LOADW(wo1, bq * 5 + 1, a * 5)
    LOADW(wo2, bq * 5 + 2, a * 5) LOADW(wo3, bq * 5 + 3, a * 5)
    LOADW(wo4, bq * 5 + 4, a * 5)
#undef LOADW

    // --- input-projection weights+bias, pre-masked to the contributing lane
    const bool eact = (bq == 0);  // even steps: reduction over bq -> bq==0 adds
    const bool oact = (a == 0);   // odd steps:  reduction over a  -> a==0 adds
    F5 wie, bie, wio, bio;
    {
        const float* pw = W_ih + a * 5;
        const float* p1 = b_ih + a * 5;
        const float* p2 = b_hh + a * 5;
        wie.v0 = eact ? pw[0] : 0.f;  bie.v0 = eact ? (p1[0] + p2[0]) : 0.f;
        wie.v1 = eact ? pw[1] : 0.f;  bie.v1 = eact ? (p1[1] + p2[1]) : 0.f;
        wie.v2 = eact ? pw[2] : 0.f;  bie.v2 = eact ? (p1[2] + p2[2]) : 0.f;
        wie.v3 = eact ? pw[3] : 0.f;  bie.v3 = eact ? (p1[3] + p2[3]) : 0.f;
        wie.v4 = eact ? pw[4] : 0.f;  bie.v4 = eact ? (p1[4] + p2[4]) : 0.f;
    }
    {
        const float* pw = W_ih + bq * 5;
        const float* p1 = b_ih + bq * 5;
        const float* p2 = b_hh + bq * 5;
        wio.v0 = oact ? pw[0] : 0.f;  bio.v0 = oact ? (p1[0] + p2[0]) : 0.f;
        wio.v1 = oact ? pw[1] : 0.f;  bio.v1 = oact ? (p1[1] + p2[1]) : 0.f;
        wio.v2 = oact ? pw[2] : 0.f;  bio.v2 = oact ? (p1[2] + p2[2]) : 0.f;
        wio.v3 = oact ? pw[3] : 0.f;  bio.v3 = oact ? (p1[3] + p2[3]) : 0.f;
        wio.v4 = oact ? pw[4] : 0.f;  bio.v4 = oact ? (p1[4] + p2[4]) : 0.f;
    }

    // pin: values become opaque asm outputs -> cannot be rematerialized
    pin5(we0); pin5(we1); pin5(we2); pin5(we3); pin5(we4);
    pin5(wo0); pin5(wo1); pin5(wo2); pin5(wo3); pin5(wo4);
    pin5(wie); pin5(bie); pin5(wio); pin5(bio);

    F5 h = {0.f, 0.f, 0.f, 0.f, 0.f};

    const float* __restrict__ xb = x + (size_t)b * TT;

    // depth-2 pipeline on the x stream
    float4 cur = *(const float4*)(xb);
    float4 nxt = *(const float4*)(xb + 4);
    for (int t4 = 0; t4 < TT; t4 += 4) {
        int tpre = t4 + 8;
        if (tpre > TT - 4) tpre = TT - 4;
        const float4 nn = *(const float4*)(xb + tpre);

        step<QP_XOR1, QP_XOR2>(cur.x, h, we0, we1, we2, we3, we4, wie, bie);
        step<ROR4,    ROR8   >(cur.y, h, wo0, wo1, wo2, wo3, wo4, wio, bio);
        step<QP_XOR1, QP_XOR2>(cur.z, h, we0, we1, we2, we3, we4, wie, bie);
        step<ROR4,    ROR8   >(cur.w, h, wo0, wo1, wo2, wo3, wo4, wio, bio);

        cur = nxt;
        nxt = nn;
    }

    // keep-alives: live ranges provably span the loop (no in-loop reload wins)
    keep5(we0); keep5(we1); keep5(we2); keep5(we3); keep5(we4);
    keep5(wo0); keep5(wo1); keep5(wo2); keep5(wo3); keep5(wo4);
    keep5(wie); keep5(bie); keep5(wio); keep5(bio);

    // After the final (odd) step, lane (a,bq) holds h[bq-slice], replicated
    // over a. Mask fc weights to a==0 lanes, dot, reduce across the group.
    float dot;
    {
        const float* pf = fc_w + bq * 5;
        float f0 = oact ? pf[0] : 0.f, f1 = oact ? pf[1] : 0.f;
        float f2 = oact ? pf[2] : 0.f, f3 = oact ? pf[3] : 0.f;
        float f4 = oact ? pf[4] : 0.f;
        dot = h.v0 * f0;
        dot = __builtin_fmaf(h.v1, f1, dot);
        dot = __builtin_fmaf(h.v2, f2, dot);
        dot = __builtin_fmaf(h.v3, f3, dot);
        dot = __builtin_fmaf(h.v4, f4, dot);
    }
    dot += __shfl_xor(dot, 1, 16);
    dot += __shfl_xor(dot, 2, 16);
    dot += __shfl_xor(dot, 4, 16);
    dot += __shfl_xor(dot, 8, 16);

    if (gl == 0)
        out[b] = dot + fc_b[0];
}

extern "C" void kernel_launch(void* const* d_in, const int* in_sizes, int n_in,
                              void* d_out, int out_size, void* d_ws, size_t ws_size,
                              hipStream_t stream) {
    const float* x    = (const float*)d_in[0];
    const float* W_ih = (const float*)d_in[1];
    const float* W_hh = (const float*)d_in[2];
    const float* b_ih = (const float*)d_in[3];
    const float* b_hh = (const float*)d_in[4];
    const float* fc_w = (const float*)d_in[5];
    const float* fc_b = (const float*)d_in[6];
    float* out = (float*)d_out;

    // 4096 batches * 16 lanes = 65536 threads; 64-thread blocks -> 1024
    // single-wave blocks, one per SIMD.
    const int block = 64;
    const int grid  = (4096 * 16) / block;  // 1024 blocks
    rnn_alt2_kernel<<<grid, block, 0, stream>>>(x, W_ih, W_hh, b_ih, b_hh,
                                                fc_w, fc_b, out);
}

// Round 8
// 192.327 us; speedup vs baseline: 1.7017x; 1.0026x over previous
//
#include <hip/hip_runtime.h>

// RNN: h_{t+1} = relu(x_t*W_ih^T + b_ih + b_hh + W_hh·h_t), out = fc(h_T).
// B=4096, T=1000, H=20.  16 lanes per batch, 1024 waves = 1 per SIMD.
//
// Alternating-role scheme (R6/R7): lane (a,bq) of each 16-lane group:
//   EVEN step: rows a-group x k-slice bq; reduce over bq = quad_perm butterfly.
//   ODD  step: rows bq-group x k-slice a; reduce over a = row_ror:4/8 folds.
// Zero redistribution instructions.
//
// R7 lesson: residency fixed (VGPR 132) but time unchanged -> the stall was
// never reloads. Static issue = 110 cyc/step but busy+idle ~ 2x that: the
// DEPTH-FIRST source order (ROWFMA = 5 dependent FMAs back-to-back; folds as
// mov+add pairs with zero gap) serialized the dependency chains, and at
// 1 wave/SIMD every bubble is wall time. This version is BREADTH-FIRST:
// column-major tiles + k-major FMAs (adjacent insts independent), folds as
// 5 dpp-movs then 5 adds (also fusable into v_add_f32_dpp).

#define TT 1000

struct F5 { float v0, v1, v2, v3, v4; };

#define PIN(v) asm volatile("" : "+v"(v))
__device__ __forceinline__ void pin5(F5& f) {
    PIN(f.v0); PIN(f.v1); PIN(f.v2); PIN(f.v3); PIN(f.v4);
}
__device__ __forceinline__ void keep5(const F5& f) {
    asm volatile("" :: "v"(f.v0), "v"(f.v1), "v"(f.v2), "v"(f.v3), "v"(f.v4));
}

template <int CTRL>
__device__ __forceinline__ float dpp_f(float v) {
    return __int_as_float(__builtin_amdgcn_update_dpp(
        0, __float_as_int(v), CTRL, 0xF, 0xF, true));
}

#define QP_XOR1 0xB1   // quad_perm [1,0,3,2]
#define QP_XOR2 0x4E   // quad_perm [2,3,0,1]
#define ROR4   0x124   // row_ror:4  (within 16-lane row)
#define ROR8   0x128   // row_ror:8

// One timestep, breadth-first. wc0..wc4 are COLUMNS of the 5x5 tile:
// wck.vj = W[row j][col k]. C1/C2 pick the reduction pattern.
template <int C1, int C2>
__device__ __forceinline__ void step(float xt, F5& h,
                                     const F5& wc0, const F5& wc1,
                                     const F5& wc2, const F5& wc3,
                                     const F5& wc4,
                                     const F5& wih, const F5& bias) {
    // init (independent of h)
    float a0 = __builtin_fmaf(xt, wih.v0, bias.v0);
    float a1 = __builtin_fmaf(xt, wih.v1, bias.v1);
    float a2 = __builtin_fmaf(xt, wih.v2, bias.v2);
    float a3 = __builtin_fmaf(xt, wih.v3, bias.v3);
    float a4 = __builtin_fmaf(xt, wih.v4, bias.v4);

    // k-major: 5 independent FMAs between any two dependent ones
#define KCOL(hk, wc)                              \
    a0 = __builtin_fmaf(hk, (wc).v0, a0);         \
    a1 = __builtin_fmaf(hk, (wc).v1, a1);         \
    a2 = __builtin_fmaf(hk, (wc).v2, a2);         \
    a3 = __builtin_fmaf(hk, (wc).v3, a3);         \
    a4 = __builtin_fmaf(hk, (wc).v4, a4);
    KCOL(h.v0, wc0) KCOL(h.v1, wc1) KCOL(h.v2, wc2) KCOL(h.v3, wc3) KCOL(h.v4, wc4)
#undef KCOL

    // fold 1: all movs, then all adds (dpp->add gap = 5 insts)
    {
        float t0 = dpp_f<C1>(a0), t1 = dpp_f<C1>(a1), t2 = dpp_f<C1>(a2),
              t3 = dpp_f<C1>(a3), t4 = dpp_f<C1>(a4);
        a0 += t0; a1 += t1; a2 += t2; a3 += t3; a4 += t4;
    }
    // fold 2
    {
        float t0 = dpp_f<C2>(a0), t1 = dpp_f<C2>(a1), t2 = dpp_f<C2>(a2),
              t3 = dpp_f<C2>(a3), t4 = dpp_f<C2>(a4);
        a0 += t0; a1 += t1; a2 += t2; a3 += t3; a4 += t4;
    }

    h.v0 = fmaxf(a0, 0.f); h.v1 = fmaxf(a1, 0.f); h.v2 = fmaxf(a2, 0.f);
    h.v3 = fmaxf(a3, 0.f); h.v4 = fmaxf(a4, 0.f);
}

__global__ void
__attribute__((amdgpu_flat_work_group_size(64, 64), amdgpu_waves_per_eu(1, 1)))
rnn_bf_kernel(const float* __restrict__ x,
              const float* __restrict__ W_ih,
              const float* __restrict__ W_hh,
              const float* __restrict__ b_ih,
              const float* __restrict__ b_hh,
              const float* __restrict__ fc_w,
              const float* __restrict__ fc_b,
              float* __restrict__ out) {
    const int tid = blockIdx.x * 64 + threadIdx.x;
    const int b   = tid >> 4;     // batch element
    const int gl  = tid & 15;     // lane in 16-lane group (DPP-row aligned)
    const int a   = gl >> 2;      // quad index
    const int bq  = gl & 3;       // position in quad

    // --- weight tiles, COLUMN-major per tile.
    // even tile: rows a-group, cols bq-group;  odd tile: transposed roles.
    F5 we0, we1, we2, we3, we4;   // wek.vj = W[a*5+j][bq*5+k]
    F5 wo0, wo1, wo2, wo3, wo4;   // wok.vj = W[bq*5+j][a*5+k]
#define LOADC(wk, k, rbase, cbase)                                           \
    { (wk).v0 = W_hh[((rbase) + 0) * 20 + (cbase) + (k)];                    \
      (wk).v1 = W_hh[((rbase) + 1) * 20 + (cbase) + (k)];                    \
      (wk).v2 = W_hh[((rbase) + 2) * 20 + (cbase) + (k)];                    \
      (wk).v3 = W_hh[((rbase) + 3) * 20 + (cbase) + (k)];                    \
      (wk).v4 = W_hh[((rbase) + 4) * 20 + (cbase) + (k)]; }
    LOADC(we0, 0, a * 5, bq * 5) LOADC(we1, 1, a * 5, bq * 5)
    LOADC(we2, 2, a * 5, bq * 5) LOADC(we3, 3, a * 5, bq * 5)
    LOADC(we4, 4, a * 5, bq * 5)
    LOADC(wo0, 0, bq * 5, a * 5) LOADC(wo1, 1, bq * 5, a * 5)
    LOADC(wo2, 2, bq * 5, a * 5) LOADC(wo3, 3, bq * 5, a * 5)
    LOADC(wo4, 4, bq * 5, a * 5)
#undef LOADC

    // --- input-projection weights+bias, pre-masked to the contributing lane
    const bool eact = (bq == 0);  // even steps: reduction over bq
    const bool oact = (a == 0);   // odd steps:  reduction over a
    F5 wie, bie, wio, bio;
    {
        const float* pw = W_ih + a * 5;
        const float* p1 = b_ih + a * 5;
        const float* p2 = b_hh + a * 5;
        wie.v0 = eact ? pw[0] : 0.f;  bie.v0 = eact ? (p1[0] + p2[0]) : 0.f;
        wie.v1 = eact ? pw[1] : 0.f;  bie.v1 = eact ? (p1[1] + p2[1]) : 0.f;
        wie.v2 = eact ? pw[2] : 0.f;  bie.v2 = eact ? (p1[2] + p2[2]) : 0.f;
        wie.v3 = eact ? pw[3] : 0.f;  bie.v3 = eact ? (p1[3] + p2[3]) : 0.f;
        wie.v4 = eact ? pw[4] : 0.f;  bie.v4 = eact ? (p1[4] + p2[4]) : 0.f;
    }
    {
        const float* pw = W_ih + bq * 5;
        const float* p1 = b_ih + bq * 5;
        const float* p2 = b_hh + bq * 5;
        wio.v0 = oact ? pw[0] : 0.f;  bio.v0 = oact ? (p1[0] + p2[0]) : 0.f;
        wio.v1 = oact ? pw[1] : 0.f;  bio.v1 = oact ? (p1[1] + p2[1]) : 0.f;
        wio.v2 = oact ? pw[2] : 0.f;  bio.v2 = oact ? (p1[2] + p2[2]) : 0.f;
        wio.v3 = oact ? pw[3] : 0.f;  bio.v3 = oact ? (p1[3] + p2[3]) : 0.f;
        wio.v4 = oact ? pw[4] : 0.f;  bio.v4 = oact ? (p1[4] + p2[4]) : 0.f;
    }

    // residency recipe from R4/R7: pins + (64,64)/(1,1) attrs + keep-alives
    pin5(we0); pin5(we1); pin5(we2); pin5(we3); pin5(we4);
    pin5(wo0); pin5(wo1); pin5(wo2); pin5(wo3); pin5(wo4);
    pin5(wie); pin5(bie); pin5(wio); pin5(bio);

    F5 h = {0.f, 0.f, 0.f, 0.f, 0.f};

    const float* __restrict__ xb = x + (size_t)b * TT;

    float4 cur = *(const float4*)(xb);
    float4 nxt = *(const float4*)(xb + 4);
    for (int t4 = 0; t4 < TT; t4 += 4) {
        int tpre = t4 + 8;
        if (tpre > TT - 4) tpre = TT - 4;
        const float4 nn = *(const float4*)(xb + tpre);

        step<QP_XOR1, QP_XOR2>(cur.x, h, we0, we1, we2, we3, we4, wie, bie);
        step<ROR4,    ROR8   >(cur.y, h, wo0, wo1, wo2, wo3, wo4, wio, bio);
        step<QP_XOR1, QP_XOR2>(cur.z, h, we0, we1, we2, we3, we4, wie, bie);
        step<ROR4,    ROR8   >(cur.w, h, wo0, wo1, wo2, wo3, wo4, wio, bio);

        cur = nxt;
        nxt = nn;
    }

    keep5(we0); keep5(we1); keep5(we2); keep5(we3); keep5(we4);
    keep5(wo0); keep5(wo1); keep5(wo2); keep5(wo3); keep5(wo4);
    keep5(wie); keep5(bie); keep5(wio); keep5(bio);

    // After the final (odd) step, lane (a,bq) holds h[bq-slice], replicated
    // over a. Mask fc weights to a==0 lanes, dot, reduce across the group.
    float dot;
    {
        const float* pf = fc_w + bq * 5;
        float f0 = oact ? pf[0] : 0.f, f1 = oact ? pf[1] : 0.f;
        float f2 = oact ? pf[2] : 0.f, f3 = oact ? pf[3] : 0.f;
        float f4 = oact ? pf[4] : 0.f;
        dot = h.v0 * f0;
        dot = __builtin_fmaf(h.v1, f1, dot);
        dot = __builtin_fmaf(h.v2, f2, dot);
        dot = __builtin_fmaf(h.v3, f3, dot);
        dot = __builtin_fmaf(h.v4, f4, dot);
    }
    dot += __shfl_xor(dot, 1, 16);
    dot += __shfl_xor(dot, 2, 16);
    dot += __shfl_xor(dot, 4, 16);
    dot += __shfl_xor(dot, 8, 16);

    if (gl == 0)
        out[b] = dot + fc_b[0];
}

extern "C" void kernel_launch(void* const* d_in, const int* in_sizes, int n_in,
                              void* d_out, int out_size, void* d_ws, size_t ws_size,
                              hipStream_t stream) {
    const float* x    = (const float*)d_in[0];
    const float* W_ih = (const float*)d_in[1];
    const float* W_hh = (const float*)d_in[2];
    const float* b_ih = (const float*)d_in[3];
    const float* b_hh = (const float*)d_in[4];
    const float* fc_w = (const float*)d_in[5];
    const float* fc_b = (const float*)d_in[6];
    float* out = (float*)d_out;

    // 4096 batches * 16 lanes = 65536 threads; 64-thread blocks -> 1024
    // single-wave blocks, one per SIMD.
    const int block = 64;
    const int grid  = (4096 * 16) / block;  // 1024 blocks
    rnn_bf_kernel<<<grid, block, 0, stream>>>(x, W_ih, W_hh, b_ih, b_hh,
                                              fc_w, fc_b, out);
}

// Round 9
// 160.058 us; speedup vs baseline: 2.0448x; 1.2016x over previous
//
#include <hip/hip_runtime.h>

// RNN: h_{t+1} = relu(x_t*W_ih^T + b_ih + b_hh + W_hh·h_t), out = fc(h_T).
// B=4096, T=1000, H=20.  16 lanes per batch, 1024 waves = 1 per SIMD.
//
// Alternating-role scheme (R6+): lane (a,bq) of each 16-lane group:
//   EVEN step: rows a-group x k-slice bq; reduce over bq = quad_perm butterfly.
//   ODD  step: rows bq-group x k-slice a; reduce over a = row_ror:4/8 folds.
// 55 VALU/step, zero redistribution.
//
// R8 lesson: residency (R7) and breadth-first ordering (R8) both landed at
// ~140 us / VALUBusy 52% -> the ~50% idle is the X-STREAM LATENCY: one
// global_load_dwordx4 per 4 steps, consumed ~8 steps after issue, every load
// an HBM-class miss (~900 cyc), and the cur=nxt copy chain forces a vmcnt
// wait every iteration with no co-resident wave to hide the shortfall.
// Fix: block prefetch. 20-step blocks (1000 = 50 blocks), two register
// blocks A/B (5 float4 each), reload each block's registers 20 steps before
// consumption -> load-to-use gap ~2200 cyc ideal, <=10 loads in flight,
// no copies, no per-iteration vmcnt(0/1).

#define TT 1000

struct F5 { float v0, v1, v2, v3, v4; };

#define PIN(v) asm volatile("" : "+v"(v))
__device__ __forceinline__ void pin5(F5& f) {
    PIN(f.v0); PIN(f.v1); PIN(f.v2); PIN(f.v3); PIN(f.v4);
}
__device__ __forceinline__ void keep5(const F5& f) {
    asm volatile("" :: "v"(f.v0), "v"(f.v1), "v"(f.v2), "v"(f.v3), "v"(f.v4));
}

template <int CTRL>
__device__ __forceinline__ float dpp_f(float v) {
    return __int_as_float(__builtin_amdgcn_update_dpp(
        0, __float_as_int(v), CTRL, 0xF, 0xF, true));
}

#define QP_XOR1 0xB1   // quad_perm [1,0,3,2]
#define QP_XOR2 0x4E   // quad_perm [2,3,0,1]
#define ROR4   0x124   // row_ror:4  (within 16-lane row)
#define ROR8   0x128   // row_ror:8

// One timestep, breadth-first, column-major tile (wck.vj = W[row j][col k]).
template <int C1, int C2>
__device__ __forceinline__ void step(float xt, F5& h,
                                     const F5& wc0, const F5& wc1,
                                     const F5& wc2, const F5& wc3,
                                     const F5& wc4,
                                     const F5& wih, const F5& bias) {
    float a0 = __builtin_fmaf(xt, wih.v0, bias.v0);
    float a1 = __builtin_fmaf(xt, wih.v1, bias.v1);
    float a2 = __builtin_fmaf(xt, wih.v2, bias.v2);
    float a3 = __builtin_fmaf(xt, wih.v3, bias.v3);
    float a4 = __builtin_fmaf(xt, wih.v4, bias.v4);

#define KCOL(hk, wc)                              \
    a0 = __builtin_fmaf(hk, (wc).v0, a0);         \
    a1 = __builtin_fmaf(hk, (wc).v1, a1);         \
    a2 = __builtin_fmaf(hk, (wc).v2, a2);         \
    a3 = __builtin_fmaf(hk, (wc).v3, a3);         \
    a4 = __builtin_fmaf(hk, (wc).v4, a4);
    KCOL(h.v0, wc0) KCOL(h.v1, wc1) KCOL(h.v2, wc2) KCOL(h.v3, wc3) KCOL(h.v4, wc4)
#undef KCOL

    {
        float t0 = dpp_f<C1>(a0), t1 = dpp_f<C1>(a1), t2 = dpp_f<C1>(a2),
              t3 = dpp_f<C1>(a3), t4 = dpp_f<C1>(a4);
        a0 += t0; a1 += t1; a2 += t2; a3 += t3; a4 += t4;
    }
    {
        float t0 = dpp_f<C2>(a0), t1 = dpp_f<C2>(a1), t2 = dpp_f<C2>(a2),
              t3 = dpp_f<C2>(a3), t4 = dpp_f<C2>(a4);
        a0 += t0; a1 += t1; a2 += t2; a3 += t3; a4 += t4;
    }

    h.v0 = fmaxf(a0, 0.f); h.v1 = fmaxf(a1, 0.f); h.v2 = fmaxf(a2, 0.f);
    h.v3 = fmaxf(a3, 0.f); h.v4 = fmaxf(a4, 0.f);
}

__global__ void
__attribute__((amdgpu_flat_work_group_size(64, 64), amdgpu_waves_per_eu(1, 1)))
rnn_pf_kernel(const float* __restrict__ x,
              const float* __restrict__ W_ih,
              const float* __restrict__ W_hh,
              const float* __restrict__ b_ih,
              const float* __restrict__ b_hh,
              const float* __restrict__ fc_w,
              const float* __restrict__ fc_b,
              float* __restrict__ out) {
    const int tid = blockIdx.x * 64 + threadIdx.x;
    const int b   = tid >> 4;     // batch element
    const int gl  = tid & 15;     // lane in 16-lane group
    const int a   = gl >> 2;      // quad index
    const int bq  = gl & 3;       // position in quad

    // --- weight tiles, column-major
    F5 we0, we1, we2, we3, we4;   // wek.vj = W[a*5+j][bq*5+k]
    F5 wo0, wo1, wo2, wo3, wo4;   // wok.vj = W[bq*5+j][a*5+k]
#define LOADC(wk, k, rbase, cbase)                                           \
    { (wk).v0 = W_hh[((rbase) + 0) * 20 + (cbase) + (k)];                    \
      (wk).v1 = W_hh[((rbase) + 1) * 20 + (cbase) + (k)];                    \
      (wk).v2 = W_hh[((rbase) + 2) * 20 + (cbase) + (k)];                    \
      (wk).v3 = W_hh[((rbase) + 3) * 20 + (cbase) + (k)];                    \
      (wk).v4 = W_hh[((rbase) + 4) * 20 + (cbase) + (k)]; }
    LOADC(we0, 0, a * 5, bq * 5) LOADC(we1, 1, a * 5, bq * 5)
    LOADC(we2, 2, a * 5, bq * 5) LOADC(we3, 3, a * 5, bq * 5)
    LOADC(we4, 4, a * 5, bq * 5)
    LOADC(wo0, 0, bq * 5, a * 5) LOADC(wo1, 1, bq * 5, a * 5)
    LOADC(wo2, 2, bq * 5, a * 5) LOADC(wo3, 3, bq * 5, a * 5)
    LOADC(wo4, 4, bq * 5, a * 5)
#undef LOADC

    const bool eact = (bq == 0);
    const bool oact = (a == 0);
    F5 wie, bie, wio, bio;
    {
        const float* pw = W_ih + a * 5;
        const float* p1 = b_ih + a * 5;
        const float* p2 = b_hh + a * 5;
        wie.v0 = eact ? pw[0] : 0.f;  bie.v0 = eact ? (p1[0] + p2[0]) : 0.f;
        wie.v1 = eact ? pw[1] : 0.f;  bie.v1 = eact ? (p1[1] + p2[1]) : 0.f;
        wie.v2 = eact ? pw[2] : 0.f;  bie.v2 = eact ? (p1[2] + p2[2]) : 0.f;
        wie.v3 = eact ? pw[3] : 0.f;  bie.v3 = eact ? (p1[3] + p2[3]) : 0.f;
        wie.v4 = eact ? pw[4] : 0.f;  bie.v4 = eact ? (p1[4] + p2[4]) : 0.f;
    }
    {
        const float* pw = W_ih + bq * 5;
        const float* p1 = b_ih + bq * 5;
        const float* p2 = b_hh + bq * 5;
        wio.v0 = oact ? pw[0] : 0.f;  bio.v0 = oact ? (p1[0] + p2[0]) : 0.f;
        wio.v1 = oact ? pw[1] : 0.f;  bio.v1 = oact ? (p1[1] + p2[1]) : 0.f;
        wio.v2 = oact ? pw[2] : 0.f;  bio.v2 = oact ? (p1[2] + p2[2]) : 0.f;
        wio.v3 = oact ? pw[3] : 0.f;  bio.v3 = oact ? (p1[3] + p2[3]) : 0.f;
        wio.v4 = oact ? pw[4] : 0.f;  bio.v4 = oact ? (p1[4] + p2[4]) : 0.f;
    }

    pin5(we0); pin5(we1); pin5(we2); pin5(we3); pin5(we4);
    pin5(wo0); pin5(wo1); pin5(wo2); pin5(wo3); pin5(wo4);
    pin5(wie); pin5(bie); pin5(wio); pin5(bio);

    F5 h = {0.f, 0.f, 0.f, 0.f, 0.f};

    const float* __restrict__ xb = x + (size_t)b * TT;

    // --- 20-step register blocks, double-buffered (A = steps 0..19 of block,
    //     B = next block). Reload each 20 steps before consumption.
#define LOAD5(P0, P1, P2, P3, P4, off)                  \
    P0 = *(const float4*)(xb + (off));                  \
    P1 = *(const float4*)(xb + (off) + 4);              \
    P2 = *(const float4*)(xb + (off) + 8);              \
    P3 = *(const float4*)(xb + (off) + 12);             \
    P4 = *(const float4*)(xb + (off) + 16);

#define STEP_E(xv) step<QP_XOR1, QP_XOR2>(xv, h, we0, we1, we2, we3, we4, wie, bie);
#define STEP_O(xv) step<ROR4,    ROR8   >(xv, h, wo0, wo1, wo2, wo3, wo4, wio, bio);
#define RUN4(Q)  STEP_E(Q.x) STEP_O(Q.y) STEP_E(Q.z) STEP_O(Q.w)
#define RUN20(P0, P1, P2, P3, P4) RUN4(P0) RUN4(P1) RUN4(P2) RUN4(P3) RUN4(P4)

    float4 A0, A1, A2, A3, A4, B0, B1, B2, B3, B4;
    LOAD5(A0, A1, A2, A3, A4, 0)    // block 0: steps 0..19
    LOAD5(B0, B1, B2, B3, B4, 20)   // block 1: steps 20..39

    for (int it = 0; it < 25; ++it) {
        const int base = it * 40;
        // clamped next-block offsets (last iteration reloads stale data, unused)
        const int na = (it < 24) ? base + 40 : 920;
        const int nb = (it < 24) ? base + 60 : 940;

        RUN20(A0, A1, A2, A3, A4)          // steps base .. base+19
        LOAD5(A0, A1, A2, A3, A4, na)      // prefetch block 2it+2
        RUN20(B0, B1, B2, B3, B4)          // steps base+20 .. base+39
        LOAD5(B0, B1, B2, B3, B4, nb)      // prefetch block 2it+3
    }

#undef RUN20
#undef RUN4
#undef STEP_E
#undef STEP_O
#undef LOAD5

    keep5(we0); keep5(we1); keep5(we2); keep5(we3); keep5(we4);
    keep5(wo0); keep5(wo1); keep5(wo2); keep5(wo3); keep5(wo4);
    keep5(wie); keep5(bie); keep5(wio); keep5(bio);

    // After step 999 (odd role), lane (a,bq) holds h[bq-slice] replicated
    // over a. Mask fc weights to a==0 lanes, dot, reduce across the group.
    float dot;
    {
        const float* pf = fc_w + bq * 5;
        float f0 = oact ? pf[0] : 0.f, f1 = oact ? pf[1] : 0.f;
        float f2 = oact ? pf[2] : 0.f, f3 = oact ? pf[3] : 0.f;
        float f4 = oact ? pf[4] : 0.f;
        dot = h.v0 * f0;
        dot = __builtin_fmaf(h.v1, f1, dot);
        dot = __builtin_fmaf(h.v2, f2, dot);
        dot = __builtin_fmaf(h.v3, f3, dot);
        dot = __builtin_fmaf(h.v4, f4, dot);
    }
    dot += __shfl_xor(dot, 1, 16);
    dot += __shfl_xor(dot, 2, 16);
    dot += __shfl_xor(dot, 4, 16);
    dot += __shfl_xor(dot, 8, 16);

    if (gl == 0)
        out[b] = dot + fc_b[0];
}

extern "C" void kernel_launch(void* const* d_in, const int* in_sizes, int n_in,
                              void* d_out, int out_size, void* d_ws, size_t ws_size,
                              hipStream_t stream) {
    const float* x    = (const float*)d_in[0];
    const float* W_ih = (const float*)d_in[1];
    const float* W_hh = (const float*)d_in[2];
    const float* b_ih = (const float*)d_in[3];
    const float* b_hh = (const float*)d_in[4];
    const float* fc_w = (const float*)d_in[5];
    const float* fc_b = (const float*)d_in[6];
    float* out = (float*)d_out;

    // 4096 batches * 16 lanes = 65536 threads; 64-thread blocks -> 1024
    // single-wave blocks, one per SIMD.
    const int block = 64;
    const int grid  = (4096 * 16) / block;  // 1024 blocks
    rnn_pf_kernel<<<grid, block, 0, stream>>>(x, W_ih, W_hh, b_ih, b_hh,
                                              fc_w, fc_b, out);
}